// Round 6
// baseline (157.756 us; speedup 1.0000x reference)
//
#include <hip/hip_runtime.h>

// LocallyConnected2d: B=16, C=4, H=W=128, K=7, PAD=3, fp32.
// out[b,o,h,w] = mask * sum_{i,t} xpad[b,i,h+dy,w+dx] * wn[o,i,h,w,t]
// cw = weight + 1 at center tap (t=24) for ALL (o,i); wn = |cw|/sum_t|cw|.
//
// R6: single fused kernel, no wsT round-trip (R5 lesson: normalized-weight
// store + 4x refetch made fused2 latency-bound at 9.6% occupancy).
//  - block=(o,h,whalf): stages its 4i x 64w x 49t raw weight panel to LDS
//    once (each weight element read from HBM exactly once chip-wide).
//  - lane=(wl 16, i 4): thread owns row (o,i,h,w); ONE pass does both
//    s += |cw| and acc[16b] += |cw|*x (1/s folded in after the loop).
//  - i-reduction via shfl_xor(16,32); 1 barrier; no atomics.
//  - LDS 50.3 KB (chunk pad 786 f4 -> max 2-way bank alias = free).

#define HW 128
#define PW 134
#define NB 16
#define NC 4
#define KK 49
#define CHUNK4 786

#define XTP_FLOATS (NC * PW * PW * NB)

__global__ __launch_bounds__(256) void lc2d_prep(const float* __restrict__ x,
                                                 float* __restrict__ xTp) {
  int idx = blockIdx.x * 256 + threadIdx.x;
  if (idx >= NC * PW * PW) return;
  int wp = idx % PW;
  int r  = idx / PW;
  int hp = r % PW;
  int i  = r / PW;
  int h = hp - 3, w = wp - 3;
  bool in = (h >= 0) & (h < HW) & (w >= 0) & (w < HW);
  float v[NB];
#pragma unroll
  for (int b = 0; b < NB; ++b)
    v[b] = in ? x[((b * NC + i) * HW + h) * HW + w] : 0.0f;
  float4* dst = (float4*)(xTp + (size_t)idx * NB);
  dst[0] = make_float4(v[0],  v[1],  v[2],  v[3]);
  dst[1] = make_float4(v[4],  v[5],  v[6],  v[7]);
  dst[2] = make_float4(v[8],  v[9],  v[10], v[11]);
  dst[3] = make_float4(v[12], v[13], v[14], v[15]);
}

__global__ __launch_bounds__(256, 3)
void lc2d_fused3(const float* __restrict__ weight,
                 const float* __restrict__ xTp,
                 float* __restrict__ out) {
  __shared__ __align__(16) float4 panel4[NC * CHUNK4];   // 50.3 KB

  const int tid = threadIdx.x;
  const int bid = blockIdx.x;
  const int o   = bid & 3;
  const int h   = (bid >> 2) & 127;
  const int wq  = bid >> 9;

#pragma unroll
  for (int ic = 0; ic < NC; ++ic) {
    const float4* g4 = (const float4*)(weight +
        (size_t)((o * NC + ic) * 16384 + h * HW + wq * 64) * KK);
#pragma unroll
    for (int k = 0; k < 4; ++k) {
      int f = tid + k * 256;
      if (f < 784) panel4[ic * CHUNK4 + f] = g4[f];
    }
  }
  __syncthreads();

  const int wl   = tid & 15;
  const int ii   = (tid >> 4) & 3;
  const int wv   = tid >> 6;
  const int wloc = wv * 16 + wl;
  const int w    = wq * 64 + wloc;

  const float* row = (const float*)panel4 + ii * (CHUNK4 * 4) + wloc * KK;
  const float4* __restrict__ xTp4 = (const float4*)xTp;

  float4 a0 = make_float4(0.f,0.f,0.f,0.f), a1 = a0, a2 = a0, a3 = a0;
  float s = 0.f;

#pragma unroll
  for (int dy = 0; dy < 7; ++dy) {
    const float4* xp = xTp4 + (size_t)((ii * PW + h + dy) * PW + w) * 4;
#pragma unroll
    for (int dx = 0; dx < 7; ++dx) {
      const int t = dy * 7 + dx;
      float v = row[t];
      if (t == 24) v += 1.f;
      float av = fabsf(v);
      s += av;
      const float4* xq = xp + dx * 4;
      float4 x0 = xq[0], x1 = xq[1], x2 = xq[2], x3 = xq[3];
      a0.x = fmaf(av, x0.x, a0.x); a0.y = fmaf(av, x0.y, a0.y);
      a0.z = fmaf(av, x0.z, a0.z); a0.w = fmaf(av, x0.w, a0.w);
      a1.x = fmaf(av, x1.x, a1.x); a1.y = fmaf(av, x1.y, a1.y);
      a1.z = fmaf(av, x1.z, a1.z); a1.w = fmaf(av, x1.w, a1.w);
      a2.x = fmaf(av, x2.x, a2.x); a2.y = fmaf(av, x2.y, a2.y);
      a2.z = fmaf(av, x2.z, a2.z); a2.w = fmaf(av, x2.w, a2.w);
      a3.x = fmaf(av, x3.x, a3.x); a3.y = fmaf(av, x3.y, a3.y);
      a3.z = fmaf(av, x3.z, a3.z); a3.w = fmaf(av, x3.w, a3.w);
    }
  }

  const float inv = 1.f / s;
  float r[16] = {a0.x*inv, a0.y*inv, a0.z*inv, a0.w*inv,
                 a1.x*inv, a1.y*inv, a1.z*inv, a1.w*inv,
                 a2.x*inv, a2.y*inv, a2.z*inv, a2.w*inv,
                 a3.x*inv, a3.y*inv, a3.z*inv, a3.w*inv};

#pragma unroll
  for (int k = 0; k < 16; ++k) {
    r[k] += __shfl_xor(r[k], 16);
    r[k] += __shfl_xor(r[k], 32);
  }

  float q0, q1, q2, q3;
  if (ii == 0)      { q0 = r[0];  q1 = r[1];  q2 = r[2];  q3 = r[3];  }
  else if (ii == 1) { q0 = r[4];  q1 = r[5];  q2 = r[6];  q3 = r[7];  }
  else if (ii == 2) { q0 = r[8];  q1 = r[9];  q2 = r[10]; q3 = r[11]; }
  else              { q0 = r[12]; q1 = r[13]; q2 = r[14]; q3 = r[15]; }

  float4 m4 = xTp4[(size_t)((o * PW + h + 3) * PW + (w + 3)) * 4 + ii];
  const int obase = h * HW + w;
  out[((ii * 4 + 0) * NC + o) * (HW * HW) + obase] = (m4.x != 0.f) ? q0 : 0.f;
  out[((ii * 4 + 1) * NC + o) * (HW * HW) + obase] = (m4.y != 0.f) ? q1 : 0.f;
  out[((ii * 4 + 2) * NC + o) * (HW * HW) + obase] = (m4.z != 0.f) ? q2 : 0.f;
  out[((ii * 4 + 3) * NC + o) * (HW * HW) + obase] = (m4.w != 0.f) ? q3 : 0.f;
}

// ---------------- fallback (no-ws): direct x, i-split blocks + atomics
__global__ __launch_bounds__(256) void lc2d_nows(const float* __restrict__ weight,
                                                 const float* __restrict__ x,
                                                 float* __restrict__ out) {
  __shared__ __align__(16) float Raw[NC * 784];
  const int tid = threadIdx.x;
  const int bid = blockIdx.x;
  const int i   = bid >> 10;
  const int r2  = bid & 1023;
  const int h   = r2 >> 3;
  const int wc  = r2 & 7;
  const int w0  = wc * 16;
  const size_t wbase = (size_t)i * 802816 + (size_t)(h * HW + w0) * KK;
#pragma unroll
  for (int k = 0; k < 4; ++k) {
    int f = tid + k * 256;
    if (f < 784) {
      int o = f / 196, g = f - o * 196;
      *(float4*)(&Raw[o * 784 + 4 * g]) =
          *(const float4*)(weight + wbase + (size_t)o * 3211264 + 4 * g);
    }
  }
  __syncthreads();
  {
    const int r = tid >> 2, q = tid & 3;
    const int rowb = (r >> 4) * 784 + (r & 15) * KK;
    const int t0 = q * 12;
    float v[13];
#pragma unroll
    for (int j = 0; j < 12; ++j) v[j] = Raw[rowb + t0 + j];
    v[12] = (q == 3) ? Raw[rowb + 48] : 0.f;
    float s = 0.f;
#pragma unroll
    for (int j = 0; j < 13; ++j) s += fabsf(v[j]);
    if (q == 2) s += fabsf(v[0] + 1.f) - fabsf(v[0]);
    s += __shfl_xor(s, 1);
    s += __shfl_xor(s, 2);
    const float inv = 1.f / s;
    if (q == 2) v[0] += 1.f;
#pragma unroll
    for (int j = 0; j < 12; ++j) Raw[rowb + t0 + j] = fabsf(v[j]) * inv;
    if (q == 3) Raw[rowb + 48] = fabsf(v[12]) * inv;
  }
  __syncthreads();
  const int b = tid & 15, pos = tid >> 4, w = w0 + pos;
  float acc[NC] = {0.f, 0.f, 0.f, 0.f};
  float xv[7];
#pragma unroll
  for (int dy = 0; dy < 7; ++dy) {
    int hh = h + dy - 3;
    bool hin = (hh >= 0) & (hh < HW);
#pragma unroll
    for (int dx = 0; dx < 7; ++dx) {
      int ww = w + dx - 3;
      bool in = hin & (ww >= 0) & (ww < HW);
      xv[dx] = in ? x[((b * NC + i) * HW + hh) * HW + ww] : 0.f;
    }
#pragma unroll
    for (int o = 0; o < NC; ++o) {
      const float* wr = &Raw[o * 784 + pos * KK + dy * 7];
#pragma unroll
      for (int dx = 0; dx < 7; ++dx) acc[o] = fmaf(xv[dx], wr[dx], acc[o]);
    }
  }
#pragma unroll
  for (int o = 0; o < NC; ++o) {
    float xc = x[((b * NC + o) * HW + h) * HW + w];
    atomicAdd(&out[((b * NC + o) * HW + h) * HW + w], (xc != 0.f) ? acc[o] : 0.f);
  }
}

extern "C" void kernel_launch(void* const* d_in, const int* in_sizes, int n_in,
                              void* d_out, int out_size, void* d_ws, size_t ws_size,
                              hipStream_t stream) {
  const float* x      = (const float*)d_in[0];   // (16,4,128,128) fp32
  const float* weight = (const float*)d_in[1];   // (1,4,4,128,128,49) fp32
  float* out = (float*)d_out;                    // (16,4,128,128) fp32

  const size_t xtp_bytes = (size_t)XTP_FLOATS * 4;   // 4.6 MB
  if (ws_size >= xtp_bytes) {
    float* xTp = (float*)d_ws;
    lc2d_prep<<<(NC * PW * PW + 255) / 256, 256, 0, stream>>>(x, xTp);
    lc2d_fused3<<<1024, 256, 0, stream>>>(weight, xTp, out);
  } else {
    hipMemsetAsync(d_out, 0, (size_t)out_size * sizeof(float), stream);
    lc2d_nows<<<4096, 256, 0, stream>>>(weight, x, out);
  }
}

// Round 7
// 156.586 us; speedup vs baseline: 1.0075x; 1.0075x over previous
//
#include <hip/hip_runtime.h>

// LocallyConnected2d: B=16, C=4, H=W=128, K=7, PAD=3, fp32.
// out[b,o,h,w] = mask * sum_{i,t} xpad[b,i,h+dy,w+dx] * wn[o,i,h,w,t]
// cw = weight + 1 at center tap (t=24) for ALL (o,i); wn = |cw|/sum_t|cw|.
//
// R7 (fused4): fixes R6's scattered-x-gather (64 lines/instr TA serialization).
//  - block = (i, h, wc16): 4096 blocks x 64 thr (1 wave). LDS = 13.3 KB
//    weight panel only -> 12 blocks/CU resident (was 1-3).
//  - weights staged once (coalesced f4, scatter to 52-padded rows so
//    compute reads are 16B-aligned ds_read_b128, bq-broadcast, ~2-way).
//  - x read COALESCED from xTp: lane=(pos,bq) -> 1024B contiguous per
//    wave-instr, L2/L3-hot. 49 f4 loads/thread.
//  - normalize fused in one pass: s[o] += |cw| inline, 1/s folded after.
//  - i-sum via fp32 atomicAdd into zeroed out (i-siblings = same XCD: bid
//    difference 1024 = 0 mod 8).

typedef float fvec4 __attribute__((ext_vector_type(4)));

#define HW 128
#define PW 134
#define NC 4
#define KK 49
#define RP 52                         // padded tap-row (16B-aligned b128 rows)
#define XTP_FLOATS (NC * PW * PW * 16)

// ---------------- prep: padded transpose x[b][i][h][w] -> xTp[i][hp][wp][b]
__global__ __launch_bounds__(256) void lc2d_prep(const float* __restrict__ x,
                                                 float* __restrict__ xTp) {
  int idx = blockIdx.x * 256 + threadIdx.x;
  if (idx >= NC * PW * PW) return;
  int wp = idx % PW;
  int r  = idx / PW;
  int hp = r % PW;
  int i  = r / PW;
  int h = hp - 3, w = wp - 3;
  bool in = (h >= 0) & (h < HW) & (w >= 0) & (w < HW);
  float v[16];
#pragma unroll
  for (int b = 0; b < 16; ++b)
    v[b] = in ? x[((b * NC + i) * HW + h) * HW + w] : 0.0f;
  float4* dst = (float4*)(xTp + (size_t)idx * 16);
  dst[0] = make_float4(v[0],  v[1],  v[2],  v[3]);
  dst[1] = make_float4(v[4],  v[5],  v[6],  v[7]);
  dst[2] = make_float4(v[8],  v[9],  v[10], v[11]);
  dst[3] = make_float4(v[12], v[13], v[14], v[15]);
}

// ---------------- fused4: block=(i,h,wc); thread=(pos16, bq4); acc[4o][4b]
__global__ __launch_bounds__(64, 3)
void lc2d_fused4(const float* __restrict__ weight,
                 const float* __restrict__ xTp,
                 float* __restrict__ out) {
  __shared__ __align__(16) float Wl[NC][16][RP];   // 13.3 KB

  const int tid = threadIdx.x;
  const int bid = blockIdx.x;
  const int i   = bid >> 10;
  const int h   = (bid >> 3) & 127;
  const int wc  = bid & 7;
  const int w0  = wc * 16;

  // ---- stage 4 o-panels (196 f4 each), coalesced; scatter to padded rows
  const float* wbase = weight + (size_t)(i * 16384 + h * HW + w0) * KK;
#pragma unroll
  for (int k = 0; k < 13; ++k) {
    int g = tid + k * 64;
    if (g < 784) {
      int o  = g / 196;
      int gl = g - o * 196;
      fvec4 v = *(const fvec4*)(wbase + (size_t)o * 3211264 + 4 * gl);
      int e = 4 * gl;                              // element = p*49 + t
#pragma unroll
      for (int j = 0; j < 4; ++j) {
        int ee = e + j;
        int p  = ee / 49;
        int t  = ee - p * 49;
        Wl[o][p][t] = v[j];
      }
    }
  }
  __syncthreads();

  const int bq  = tid & 3;                         // b-quad (lane-fastest)
  const int pos = tid >> 2;                        // 0..15 w within tile
  const fvec4* __restrict__ xp = (const fvec4*)xTp +
      ((size_t)(i * PW + h) * PW + (w0 + pos)) * 4 + bq;

  float s0 = 0.f, s1 = 0.f, s2 = 0.f, s3 = 0.f;
  fvec4 a0 = {0.f,0.f,0.f,0.f}, a1 = a0, a2 = a0, a3 = a0;

#pragma unroll
  for (int tg = 0; tg < 12; ++tg) {                // taps 0..47, b128 weights
    fvec4 q0 = *(const fvec4*)&Wl[0][pos][tg * 4];
    fvec4 q1 = *(const fvec4*)&Wl[1][pos][tg * 4];
    fvec4 q2 = *(const fvec4*)&Wl[2][pos][tg * 4];
    fvec4 q3 = *(const fvec4*)&Wl[3][pos][tg * 4];
#pragma unroll
    for (int j = 0; j < 4; ++j) {
      const int t  = tg * 4 + j;
      const int dy = t / 7, dx = t - dy * 7;
      fvec4 x4 = xp[(dy * PW + dx) * 4];           // coalesced 1KB/wave, L2-hot
      float wa = q0[j], wb = q1[j], wcv = q2[j], wd = q3[j];
      if (t == 24) { wa += 1.f; wb += 1.f; wcv += 1.f; wd += 1.f; }
      float v0 = fabsf(wa), v1 = fabsf(wb), v2 = fabsf(wcv), v3 = fabsf(wd);
      s0 += v0; s1 += v1; s2 += v2; s3 += v3;
      a0 += x4 * v0; a1 += x4 * v1; a2 += x4 * v2; a3 += x4 * v3;
    }
  }
  {                                                // tap t=48 (dy=6,dx=6)
    fvec4 x4 = xp[(6 * PW + 6) * 4];
    float v0 = fabsf(Wl[0][pos][48]), v1 = fabsf(Wl[1][pos][48]);
    float v2 = fabsf(Wl[2][pos][48]), v3 = fabsf(Wl[3][pos][48]);
    s0 += v0; s1 += v1; s2 += v2; s3 += v3;
    a0 += x4 * v0; a1 += x4 * v1; a2 += x4 * v2; a3 += x4 * v3;
  }

  // fold the per-(o,i,h,w)-row L1 scale in once
  a0 *= (1.f / s0); a1 *= (1.f / s1); a2 *= (1.f / s2); a3 *= (1.f / s3);

  // ---- mask (x[b,o,h,w] != 0) + atomic accumulate over i-blocks ----
  const fvec4* __restrict__ xc = (const fvec4*)xTp;
  const int ob = h * HW + w0 + pos;
#pragma unroll
  for (int o = 0; o < 4; ++o) {
    fvec4 m = xc[((size_t)(o * PW + h + 3) * PW + (w0 + pos + 3)) * 4 + bq];
    fvec4 a = (o == 0) ? a0 : (o == 1) ? a1 : (o == 2) ? a2 : a3;
#pragma unroll
    for (int jb = 0; jb < 4; ++jb) {
      float r = (m[jb] != 0.f) ? a[jb] : 0.f;
      atomicAdd(&out[(size_t)((bq * 4 + jb) * NC + o) * 16384 + ob], r);
    }
  }
}

// ---------------- fallback (no-ws): direct x, i-split blocks + atomics
__global__ __launch_bounds__(256) void lc2d_nows(const float* __restrict__ weight,
                                                 const float* __restrict__ x,
                                                 float* __restrict__ out) {
  __shared__ __align__(16) float Raw[NC * 784];
  const int tid = threadIdx.x;
  const int bid = blockIdx.x;
  const int i   = bid >> 10;
  const int r2  = bid & 1023;
  const int h   = r2 >> 3;
  const int wc  = r2 & 7;
  const int w0  = wc * 16;
  const size_t wbase = (size_t)i * 802816 + (size_t)(h * HW + w0) * KK;
#pragma unroll
  for (int k = 0; k < 4; ++k) {
    int f = tid + k * 256;
    if (f < 784) {
      int o = f / 196, g = f - o * 196;
      *(float4*)(&Raw[o * 784 + 4 * g]) =
          *(const float4*)(weight + wbase + (size_t)o * 3211264 + 4 * g);
    }
  }
  __syncthreads();
  {
    const int r = tid >> 2, q = tid & 3;
    const int rowb = (r >> 4) * 784 + (r & 15) * KK;
    const int t0 = q * 12;
    float v[13];
#pragma unroll
    for (int j = 0; j < 12; ++j) v[j] = Raw[rowb + t0 + j];
    v[12] = (q == 3) ? Raw[rowb + 48] : 0.f;
    float s = 0.f;
#pragma unroll
    for (int j = 0; j < 13; ++j) s += fabsf(v[j]);
    if (q == 2) s += fabsf(v[0] + 1.f) - fabsf(v[0]);
    s += __shfl_xor(s, 1);
    s += __shfl_xor(s, 2);
    const float inv = 1.f / s;
    if (q == 2) v[0] += 1.f;
#pragma unroll
    for (int j = 0; j < 12; ++j) Raw[rowb + t0 + j] = fabsf(v[j]) * inv;
    if (q == 3) Raw[rowb + 48] = fabsf(v[12]) * inv;
  }
  __syncthreads();
  const int b = tid & 15, pos = tid >> 4, w = w0 + pos;
  float acc[NC] = {0.f, 0.f, 0.f, 0.f};
  float xv[7];
#pragma unroll
  for (int dy = 0; dy < 7; ++dy) {
    int hh = h + dy - 3;
    bool hin = (hh >= 0) & (hh < HW);
#pragma unroll
    for (int dx = 0; dx < 7; ++dx) {
      int ww = w + dx - 3;
      bool in = hin & (ww >= 0) & (ww < HW);
      xv[dx] = in ? x[((b * NC + i) * HW + hh) * HW + ww] : 0.f;
    }
#pragma unroll
    for (int o = 0; o < NC; ++o) {
      const float* wr = &Raw[o * 784 + pos * KK + dy * 7];
#pragma unroll
      for (int dx = 0; dx < 7; ++dx) acc[o] = fmaf(xv[dx], wr[dx], acc[o]);
    }
  }
#pragma unroll
  for (int o = 0; o < NC; ++o) {
    float xc = x[((b * NC + o) * HW + h) * HW + w];
    atomicAdd(&out[((b * NC + o) * HW + h) * HW + w], (xc != 0.f) ? acc[o] : 0.f);
  }
}

extern "C" void kernel_launch(void* const* d_in, const int* in_sizes, int n_in,
                              void* d_out, int out_size, void* d_ws, size_t ws_size,
                              hipStream_t stream) {
  const float* x      = (const float*)d_in[0];   // (16,4,128,128) fp32
  const float* weight = (const float*)d_in[1];   // (1,4,4,128,128,49) fp32
  float* out = (float*)d_out;                    // (16,4,128,128) fp32

  hipMemsetAsync(d_out, 0, (size_t)out_size * sizeof(float), stream);

  const size_t xtp_bytes = (size_t)XTP_FLOATS * 4;   // 4.6 MB
  if (ws_size >= xtp_bytes) {
    float* xTp = (float*)d_ws;
    lc2d_prep<<<(NC * PW * PW + 255) / 256, 256, 0, stream>>>(x, xTp);
    lc2d_fused4<<<4096, 64, 0, stream>>>(weight, xTp, out);
  } else {
    lc2d_nows<<<4096, 256, 0, stream>>>(weight, x, out);
  }
}

// Round 8
// 121.679 us; speedup vs baseline: 1.2965x; 1.2869x over previous
//
#include <hip/hip_runtime.h>

// LocallyConnected2d: B=16, C=4, H=W=128, K=7, PAD=3, fp32.
// out[b,o,h,w] = mask * sum_{i,t} xpad[b,i,h+dy,w+dx] * wn[o,i,h,w,t]
// cw = weight + 1 at center tap (t=24) for ALL (o,i); wn = |cw|/sum_t|cw|.
//
// R8 (fused5): R7 minus atomics (WRITE was 110MB vs 4MB of output).
//  - block=(wc8,h): 2048 x 64 thr; i-loop INSIDE block -> every output
//    stored exactly once, no memset, no atomics.
//  - all 16 (o,i) weight panels staged once to LDS (each weight element
//    fetched from HBM exactly once chip-wide); 26.6 KB -> 6 blocks/CU
//    resident, 8 assigned -> staging overlaps other blocks' compute.
//  - 52-padded LDS rows: compute reads are 16B-aligned ds_read_b128,
//    8 distinct banks per instr (pos rows), bp-broadcast -> conflict-free.
//  - x as contiguous fvec2 from xTp (lane=(pos,bp) -> 512B/wave), L2-hot.
//  - normalize fused: one pass accumulates s_oi AND tmp_oi += |cw|*x;
//    acc_o += tmp_oi * (1/s_oi) per i.
//  - bid = wc*128+h: blocks sharing a 64B out line are co-XCD (write-combine).

typedef float fvec4 __attribute__((ext_vector_type(4)));
typedef float fvec2 __attribute__((ext_vector_type(2)));

#define HW 128
#define PW 134
#define NC 4
#define KK 49
#define WC 8                          // w-stripe per block
#define RP 52                         // padded tap-row (16B-aligned b128)
#define XTP_FLOATS (NC * PW * PW * 16)

// ---------------- prep: padded transpose x[b][i][h][w] -> xTp[i][hp][wp][b]
__global__ __launch_bounds__(256) void lc2d_prep(const float* __restrict__ x,
                                                 float* __restrict__ xTp) {
  int idx = blockIdx.x * 256 + threadIdx.x;
  if (idx >= NC * PW * PW) return;
  int wp = idx % PW;
  int r  = idx / PW;
  int hp = r % PW;
  int i  = r / PW;
  int h = hp - 3, w = wp - 3;
  bool in = (h >= 0) & (h < HW) & (w >= 0) & (w < HW);
  float v[16];
#pragma unroll
  for (int b = 0; b < 16; ++b)
    v[b] = in ? x[((b * NC + i) * HW + h) * HW + w] : 0.0f;
  float4* dst = (float4*)(xTp + (size_t)idx * 16);
  dst[0] = make_float4(v[0],  v[1],  v[2],  v[3]);
  dst[1] = make_float4(v[4],  v[5],  v[6],  v[7]);
  dst[2] = make_float4(v[8],  v[9],  v[10], v[11]);
  dst[3] = make_float4(v[12], v[13], v[14], v[15]);
}

// ---------------- fused5: block=(wc,h); thread=(pos8,bp8); acc[4o][2b]
__global__ __launch_bounds__(64)
void lc2d_fused5(const float* __restrict__ weight,
                 const float* __restrict__ xTp,
                 float* __restrict__ out) {
  __shared__ __align__(16) float Wl[16][WC][RP];   // 26.6 KB

  const int tid = threadIdx.x;
  const int bid = blockIdx.x;
  const int wc  = bid >> 7;          // 0..15 (slow index: co-XCD line sharing)
  const int h   = bid & 127;
  const int w0  = wc * WC;

  // ---- stage 16 panels (98 f4 each = 1568 f4), coalesced linear reads,
  //      scalar scatter into 52-padded rows (8-way write alias, small cost)
  const float* wb = weight + (size_t)(h * HW + w0) * KK;
#pragma unroll
  for (int k = 0; k < 25; ++k) {
    int f = tid + k * 64;
    if (f < 1568) {
      int oi = f / 98;               // panel = (o*4+i)
      int fl = f - oi * 98;
      fvec4 v = *(const fvec4*)(wb + (size_t)oi * 802816 + 4 * fl);
      int e = 4 * fl;                // element = p*49 + t within panel
#pragma unroll
      for (int j = 0; j < 4; ++j) {
        int ee = e + j;
        int p  = ee / 49;
        int t  = ee - p * 49;
        Wl[oi][p][t] = v[j];
      }
    }
  }
  __syncthreads();

  const int bp  = tid & 7;           // b-pair (lane-fastest -> x coalesced)
  const int pos = tid >> 3;          // 0..7 w within stripe

  fvec2 acc0 = {0.f, 0.f}, acc1 = acc0, acc2 = acc0, acc3 = acc0;

  for (int i = 0; i < NC; ++i) {
    const float* xb = xTp + ((size_t)(i * PW + h) * PW + (w0 + pos)) * 16 + 2 * bp;
    fvec2 t0 = {0.f, 0.f}, t1 = t0, t2 = t0, t3 = t0;
    float s0 = 0.f, s1 = 0.f, s2 = 0.f, s3 = 0.f;
#pragma unroll
    for (int tg = 0; tg < 12; ++tg) {            // taps 0..47
      fvec4 q0 = *(const fvec4*)&Wl[0 * 4 + i][pos][tg * 4];
      fvec4 q1 = *(const fvec4*)&Wl[1 * 4 + i][pos][tg * 4];
      fvec4 q2 = *(const fvec4*)&Wl[2 * 4 + i][pos][tg * 4];
      fvec4 q3 = *(const fvec4*)&Wl[3 * 4 + i][pos][tg * 4];
#pragma unroll
      for (int j = 0; j < 4; ++j) {
        const int t  = tg * 4 + j;
        const int dy = t / 7, dx = t - dy * 7;
        fvec2 xv = *(const fvec2*)(xb + (dy * PW + dx) * 16);  // 512B/wave, hot
        float wa = q0[j], wbv = q1[j], wcv = q2[j], wd = q3[j];
        if (t == 24) { wa += 1.f; wbv += 1.f; wcv += 1.f; wd += 1.f; }
        float a0 = fabsf(wa), a1 = fabsf(wbv), a2 = fabsf(wcv), a3 = fabsf(wd);
        s0 += a0; s1 += a1; s2 += a2; s3 += a3;
        t0 += xv * a0; t1 += xv * a1; t2 += xv * a2; t3 += xv * a3;
      }
    }
    {                                            // tap t=48 (dy=6,dx=6)
      fvec2 xv = *(const fvec2*)(xb + (6 * PW + 6) * 16);
      float a0 = fabsf(Wl[0 * 4 + i][pos][48]);
      float a1 = fabsf(Wl[1 * 4 + i][pos][48]);
      float a2 = fabsf(Wl[2 * 4 + i][pos][48]);
      float a3 = fabsf(Wl[3 * 4 + i][pos][48]);
      s0 += a0; s1 += a1; s2 += a2; s3 += a3;
      t0 += xv * a0; t1 += xv * a1; t2 += xv * a2; t3 += xv * a3;
    }
    // fold this (o,i,h,w)-row's L1 scale in once
    acc0 += t0 * (1.f / s0);
    acc1 += t1 * (1.f / s1);
    acc2 += t2 * (1.f / s2);
    acc3 += t3 * (1.f / s3);
  }

  // ---- mask (x[b,o,h,w] != 0) + direct store (each output written once)
  const int obase = h * HW + w0 + pos;
#pragma unroll
  for (int o = 0; o < NC; ++o) {
    fvec2 m = *(const fvec2*)(xTp +
        ((size_t)(o * PW + h + 3) * PW + (w0 + pos + 3)) * 16 + 2 * bp);
    fvec2 a = (o == 0) ? acc0 : (o == 1) ? acc1 : (o == 2) ? acc2 : acc3;
    out[(size_t)((2 * bp + 0) * NC + o) * 16384 + obase] = (m[0] != 0.f) ? a[0] : 0.f;
    out[(size_t)((2 * bp + 1) * NC + o) * 16384 + obase] = (m[1] != 0.f) ? a[1] : 0.f;
  }
}

// ---------------- fallback (no-ws): direct x, i-split blocks + atomics
__global__ __launch_bounds__(256) void lc2d_nows(const float* __restrict__ weight,
                                                 const float* __restrict__ x,
                                                 float* __restrict__ out) {
  __shared__ __align__(16) float Raw[NC * 784];
  const int tid = threadIdx.x;
  const int bid = blockIdx.x;
  const int i   = bid >> 10;
  const int r2  = bid & 1023;
  const int h   = r2 >> 3;
  const int wcc = r2 & 7;
  const int w0  = wcc * 16;
  const size_t wbase = (size_t)i * 802816 + (size_t)(h * HW + w0) * KK;
#pragma unroll
  for (int k = 0; k < 4; ++k) {
    int f = tid + k * 256;
    if (f < 784) {
      int o = f / 196, g = f - o * 196;
      *(float4*)(&Raw[o * 784 + 4 * g]) =
          *(const float4*)(weight + wbase + (size_t)o * 3211264 + 4 * g);
    }
  }
  __syncthreads();
  {
    const int r = tid >> 2, q = tid & 3;
    const int rowb = (r >> 4) * 784 + (r & 15) * KK;
    const int t0 = q * 12;
    float v[13];
#pragma unroll
    for (int j = 0; j < 12; ++j) v[j] = Raw[rowb + t0 + j];
    v[12] = (q == 3) ? Raw[rowb + 48] : 0.f;
    float s = 0.f;
#pragma unroll
    for (int j = 0; j < 13; ++j) s += fabsf(v[j]);
    if (q == 2) s += fabsf(v[0] + 1.f) - fabsf(v[0]);
    s += __shfl_xor(s, 1);
    s += __shfl_xor(s, 2);
    const float inv = 1.f / s;
    if (q == 2) v[0] += 1.f;
#pragma unroll
    for (int j = 0; j < 12; ++j) Raw[rowb + t0 + j] = fabsf(v[j]) * inv;
    if (q == 3) Raw[rowb + 48] = fabsf(v[12]) * inv;
  }
  __syncthreads();
  const int b = tid & 15, pos = tid >> 4, w = w0 + pos;
  float acc[NC] = {0.f, 0.f, 0.f, 0.f};
  float xv[7];
#pragma unroll
  for (int dy = 0; dy < 7; ++dy) {
    int hh = h + dy - 3;
    bool hin = (hh >= 0) & (hh < HW);
#pragma unroll
    for (int dx = 0; dx < 7; ++dx) {
      int ww = w + dx - 3;
      bool in = hin & (ww >= 0) & (ww < HW);
      xv[dx] = in ? x[((b * NC + i) * HW + hh) * HW + ww] : 0.f;
    }
#pragma unroll
    for (int o = 0; o < NC; ++o) {
      const float* wr = &Raw[o * 784 + pos * KK + dy * 7];
#pragma unroll
      for (int dx = 0; dx < 7; ++dx) acc[o] = fmaf(xv[dx], wr[dx], acc[o]);
    }
  }
#pragma unroll
  for (int o = 0; o < NC; ++o) {
    float xc = x[((b * NC + o) * HW + h) * HW + w];
    atomicAdd(&out[((b * NC + o) * HW + h) * HW + w], (xc != 0.f) ? acc[o] : 0.f);
  }
}

extern "C" void kernel_launch(void* const* d_in, const int* in_sizes, int n_in,
                              void* d_out, int out_size, void* d_ws, size_t ws_size,
                              hipStream_t stream) {
  const float* x      = (const float*)d_in[0];   // (16,4,128,128) fp32
  const float* weight = (const float*)d_in[1];   // (1,4,4,128,128,49) fp32
  float* out = (float*)d_out;                    // (16,4,128,128) fp32

  const size_t xtp_bytes = (size_t)XTP_FLOATS * 4;   // 4.6 MB
  if (ws_size >= xtp_bytes) {
    float* xTp = (float*)d_ws;
    lc2d_prep<<<(NC * PW * PW + 255) / 256, 256, 0, stream>>>(x, xTp);
    lc2d_fused5<<<2048, 64, 0, stream>>>(weight, xTp, out);
  } else {
    hipMemsetAsync(d_out, 0, (size_t)out_size * sizeof(float), stream);
    lc2d_nows<<<4096, 256, 0, stream>>>(weight, x, out);
  }
}